// Round 5
// baseline (1043.560 us; speedup 1.0000x reference)
//
#include <hip/hip_runtime.h>
#include <math.h>

// Problem constants (fixed by setup_inputs)
#define BB 4
#define HH 128
#define DD 512
#define WW 512
#define GG 72
#define PP 65536
#define CHUNK 256
#define NCHUNK (PP / CHUNK)          // 256
#define HDW (HH * DD * WW)           // 33,554,432
#define NBRICK (HDW / 8)             // 4,194,304 bricks of 2x2x2 voxels
#define CPB 4                        // chunks per density block
#define NPART (NCHUNK / CPB)         // 64 dist partials per g (fast path)

typedef _Float16 half4 __attribute__((ext_vector_type(4)));
typedef _Float16 half8 __attribute__((ext_vector_type(8)));
typedef float f4 __attribute__((ext_vector_type(4)));   // NT-load-compatible

// ---------------------------------------------------------------------------
// Transpose + quantize into 64B bricks:
//   ct [B,H,D,W] fp32  ->  tv bricks: brick(bz,by,bx) holds 2x2x2 voxels x 4
//   batches fp16, inner layout [oz][oy][ox][b] -> 32 halves = 64 B = 1 line.
// One thread per brick-PAIR (adjacent in x): f4 NT reads, 128 B write.
// NT on ct reads so the 512 MiB stream doesn't evict the tv writes from L3 —
// the density pass depends on tv being L3-resident.
// ---------------------------------------------------------------------------
__global__ __launch_bounds__(256) void k_transpose(
    const float* __restrict__ ct, _Float16* __restrict__ tv)
{
    const int n2  = blockIdx.x * 256 + threadIdx.x;  // brick-pair index
    const int bxp = n2 & 127;                        // 128 pairs per x-row
    const int by  = (n2 >> 7) & 255;                 // DD/2
    const int bz  = n2 >> 15;                        // HH/2
    const size_t base = ((size_t)(2 * bz) * DD + 2 * by) * WW + 4 * bxp;

    half8 o00, o01, o02, o03;   // brick 0: inner pairs (oz,oy) = 00,01,10,11
    half8 o10, o11, o12, o13;   // brick 1
#pragma unroll
    for (int b = 0; b < BB; ++b) {
        const float* v = ct + (size_t)b * HDW + base;
        const f4 f00 = __builtin_nontemporal_load((const f4*)(v));
        const f4 f01 = __builtin_nontemporal_load((const f4*)(v + WW));
        const f4 f10 = __builtin_nontemporal_load((const f4*)(v + (size_t)DD * WW));
        const f4 f11 = __builtin_nontemporal_load((const f4*)(v + (size_t)DD * WW + WW));
        o00[b] = (_Float16)f00[0]; o00[4 + b] = (_Float16)f00[1];
        o01[b] = (_Float16)f01[0]; o01[4 + b] = (_Float16)f01[1];
        o02[b] = (_Float16)f10[0]; o02[4 + b] = (_Float16)f10[1];
        o03[b] = (_Float16)f11[0]; o03[4 + b] = (_Float16)f11[1];
        o10[b] = (_Float16)f00[2]; o10[4 + b] = (_Float16)f00[3];
        o11[b] = (_Float16)f01[2]; o11[4 + b] = (_Float16)f01[3];
        o12[b] = (_Float16)f10[2]; o12[4 + b] = (_Float16)f10[3];
        o13[b] = (_Float16)f11[2]; o13[4 + b] = (_Float16)f11[3];
    }
    _Float16* dst = tv + (size_t)n2 * 64;   // two consecutive 64 B bricks
    *(half8*)(dst)      = o00;
    *(half8*)(dst + 8)  = o01;
    *(half8*)(dst + 16) = o02;
    *(half8*)(dst + 24) = o03;
    *(half8*)(dst + 32) = o10;
    *(half8*)(dst + 40) = o11;
    *(half8*)(dst + 48) = o12;
    *(half8*)(dst + 56) = o13;
}

// half-element offset of corner voxel (zc,yc,xc) in the brick volume
__device__ __forceinline__ int brick_off(int zc, int yc, int xc)
{
    const int brick = ((zc >> 1) << 16) | ((yc >> 1) << 8) | (xc >> 1);
    const int inner = ((zc & 1) << 2) | ((yc & 1) << 1) | (xc & 1);
    return (brick << 5) | (inner << 2);
}

struct PS {
    int i[8];
    float xd, yd, zd;
};

__device__ __forceinline__ PS setup_brick(float cx, float cy, float cz)
{
    const float x = fminf(fmaxf(cx, 0.0f), (float)(WW - 1));
    const float y = fminf(fmaxf(cy, 0.0f), (float)(DD - 1));
    const float z = fminf(fmaxf(cz, 0.0f), (float)(HH - 1));
    const int x0 = (int)floorf(x);
    const int y0 = (int)floorf(y);
    const int z0 = (int)floorf(z);
    const int x1 = min(x0 + 1, WW - 1);
    const int y1 = min(y0 + 1, DD - 1);
    const int z1 = min(z0 + 1, HH - 1);
    PS s;
    s.xd = x - (float)x0;
    s.yd = y - (float)y0;
    s.zd = z - (float)z0;
    s.i[0] = brick_off(z0, y0, x0); s.i[1] = brick_off(z0, y0, x1);
    s.i[2] = brick_off(z0, y1, x0); s.i[3] = brick_off(z0, y1, x1);
    s.i[4] = brick_off(z1, y0, x0); s.i[5] = brick_off(z1, y0, x1);
    s.i[6] = brick_off(z1, y1, x0); s.i[7] = brick_off(z1, y1, x1);
    return s;
}

__device__ __forceinline__ void gather8(
    const _Float16* __restrict__ tv, const PS& s, half4 A[8])
{
#pragma unroll
    for (int k = 0; k < 8; ++k) A[k] = *(const half4*)(tv + (size_t)s.i[k]);
}

__device__ __forceinline__ void lerp_store(
    const half4 A[8], const PS& s, float dens[BB],
    float* __restrict__ density, int g, int p)
{
#pragma unroll
    for (int b = 0; b < BB; ++b) {
        const float c000 = (float)A[0][b], c001 = (float)A[1][b];
        const float c010 = (float)A[2][b], c011 = (float)A[3][b];
        const float c100 = (float)A[4][b], c101 = (float)A[5][b];
        const float c110 = (float)A[6][b], c111 = (float)A[7][b];
        const float c00 = c000 * (1.0f - s.xd) + c001 * s.xd;
        const float c01 = c010 * (1.0f - s.xd) + c011 * s.xd;
        const float c10 = c100 * (1.0f - s.xd) + c101 * s.xd;
        const float c11 = c110 * (1.0f - s.xd) + c111 * s.xd;
        const float c0  = c00 * (1.0f - s.yd) + c01 * s.yd;
        const float c1  = c10 * (1.0f - s.yd) + c11 * s.yd;
        dens[b] = c0 * (1.0f - s.zd) + c1 * s.zd;
        __builtin_nontemporal_store(dens[b],
            density + ((size_t)(b * GG + g)) * PP + p);
    }
}

// ---------------------------------------------------------------------------
// Density kernel, single pass, 4 chunks per block (4 points per thread):
// 32 unmasked outstanding gather loads per thread for max MLP; coord staging
// and block reduction amortized over 4 chunks. tv is L3-resident after the
// transpose; all streaming traffic (coords, density out) is non-temporal so
// it stays resident. Each block owns chunks c0..c0+3 exclusively ->
// chunk_sums and dist_part written with plain stores (no atomics/memset).
// grid = (NCHUNK/4, GG), block = 256.
// ---------------------------------------------------------------------------
__global__ __launch_bounds__(256) void k_density_h(
    const _Float16* __restrict__ tv,    // brick volume fp16
    const float* __restrict__ coords,   // [G, P, 3]
    float* __restrict__ density,        // [B*G, P]  (aliases d_out)
    float* __restrict__ chunk_sums,     // [B*G, NCHUNK]
    float* __restrict__ dist_part)      // [G, NPART]
{
    const int cquad = blockIdx.x;            // handles chunks c0 .. c0+3
    const int g     = blockIdx.y;
    const int t     = threadIdx.x;
    const int c0    = cquad * CPB;
    const int p0    = c0 * CHUNK + t;        // point j lives at p0 + 256*j

    __shared__ float cbuf[(CPB * CHUNK + 1) * 3];
    const bool last  = (cquad == NPART - 1);
    const int  nload = last ? CPB * CHUNK * 3 : (CPB * CHUNK + 1) * 3;
    const float* src = coords + ((size_t)g * PP + (size_t)c0 * CHUNK) * 3;
    for (int i = t; i < nload; i += 256)
        cbuf[i] = __builtin_nontemporal_load(src + i);
    __syncthreads();

    float cx[CPB], cy[CPB], cz[CPB];
    float dist_tot = 0.0f;
#pragma unroll
    for (int j = 0; j < CPB; ++j) {
        const int q = t + 256 * j;
        cx[j] = cbuf[3 * q + 0];
        cy[j] = cbuf[3 * q + 1];
        cz[j] = cbuf[3 * q + 2];
        if (!(last && j == CPB - 1 && t == CHUNK - 1)) {
            const float dx = cbuf[3 * q + 3] - cx[j];
            const float dy = cbuf[3 * q + 4] - cy[j];
            const float dz = cbuf[3 * q + 5] - cz[j];
            dist_tot += sqrtf(dx * dx + dy * dy + dz * dz);
        }
    }

    PS s[CPB];
#pragma unroll
    for (int j = 0; j < CPB; ++j) s[j] = setup_brick(cx[j], cy[j], cz[j]);

    // Issue all 32 gathers before the lerps so they overlap.
    half4 A[CPB][8];
#pragma unroll
    for (int j = 0; j < CPB; ++j) gather8(tv, s[j], A[j]);

    float dens[CPB][BB];
#pragma unroll
    for (int j = 0; j < CPB; ++j)
        lerp_store(A[j], s[j], dens[j], density, g, p0 + 256 * j);

    // Fused block reduction: 16 chunk sums + 1 dist total.
    __shared__ float wsum[4][17];
    const int lane = t & 63;
    const int wid  = t >> 6;
    float r[17];
#pragma unroll
    for (int j = 0; j < CPB; ++j)
#pragma unroll
        for (int b = 0; b < BB; ++b) r[j * BB + b] = dens[j][b];
    r[16] = dist_tot;
#pragma unroll
    for (int off = 32; off > 0; off >>= 1) {
#pragma unroll
        for (int k = 0; k < 17; ++k) r[k] += __shfl_xor(r[k], off);
    }
    if (lane == 0) {
#pragma unroll
        for (int k = 0; k < 17; ++k) wsum[wid][k] = r[k];
    }
    __syncthreads();
    if (t == 0) {
        float sarr[17];
#pragma unroll
        for (int k = 0; k < 17; ++k)
            sarr[k] = wsum[0][k] + wsum[1][k] + wsum[2][k] + wsum[3][k];
#pragma unroll
        for (int j = 0; j < CPB; ++j)
#pragma unroll
            for (int b = 0; b < BB; ++b)
                chunk_sums[((size_t)(b * GG + g)) * NCHUNK + c0 + j] = sarr[j * BB + b];
        dist_part[g * NPART + cquad] = sarr[16];
    }
}

// ---------------------------------------------------------------------------
// Fallback density kernel (fp32 direct gather) — used if ws too small.
// Writes dist_part with NCHUNK partials per g.
// ---------------------------------------------------------------------------
__global__ __launch_bounds__(256) void k_density(
    const float* __restrict__ ct,
    const float* __restrict__ coords,
    float* __restrict__ density,
    float* __restrict__ chunk_sums,
    float* __restrict__ dist_part)      // [G, NCHUNK]
{
    const int chunk = blockIdx.x;
    const int g     = blockIdx.y;
    const int t     = threadIdx.x;
    const int p     = chunk * CHUNK + t;

    __shared__ float cbuf[(CHUNK + 1) * 3];
    const int nload = (chunk == NCHUNK - 1) ? CHUNK * 3 : (CHUNK + 1) * 3;
    const float* src = coords + ((size_t)g * PP + (size_t)chunk * CHUNK) * 3;
    for (int i = t; i < nload; i += CHUNK) cbuf[i] = src[i];
    __syncthreads();

    const float cx = cbuf[3 * t + 0];
    const float cy = cbuf[3 * t + 1];
    const float cz = cbuf[3 * t + 2];

    float dist = 0.0f;
    if (p < PP - 1) {
        const int nt = 3 * (t + 1);
        const float dx = cbuf[nt + 0] - cx;
        const float dy = cbuf[nt + 1] - cy;
        const float dz = cbuf[nt + 2] - cz;
        dist = sqrtf(dx * dx + dy * dy + dz * dz);
    }

    const float x = fminf(fmaxf(cx, 0.0f), (float)(WW - 1));
    const float y = fminf(fmaxf(cy, 0.0f), (float)(DD - 1));
    const float z = fminf(fmaxf(cz, 0.0f), (float)(HH - 1));
    const int x0 = (int)floorf(x);
    const int y0 = (int)floorf(y);
    const int z0 = (int)floorf(z);
    const int x1 = min(x0 + 1, WW - 1);
    const int y1 = min(y0 + 1, DD - 1);
    const int z1 = min(z0 + 1, HH - 1);
    const float xd = x - (float)x0, yd = y - (float)y0, zd = z - (float)z0;

    const int b00 = (z0 * DD + y0) * WW;
    const int b01 = (z0 * DD + y1) * WW;
    const int b10 = (z1 * DD + y0) * WW;
    const int b11 = (z1 * DD + y1) * WW;

    float dens[BB];
#pragma unroll
    for (int b = 0; b < BB; ++b) {
        const float* v = ct + (size_t)b * HDW;
        const float c000 = v[b00 + x0], c001 = v[b00 + x1];
        const float c010 = v[b01 + x0], c011 = v[b01 + x1];
        const float c100 = v[b10 + x0], c101 = v[b10 + x1];
        const float c110 = v[b11 + x0], c111 = v[b11 + x1];
        const float c00 = c000 * (1.0f - xd) + c001 * xd;
        const float c01 = c010 * (1.0f - xd) + c011 * xd;
        const float c10 = c100 * (1.0f - xd) + c101 * xd;
        const float c11 = c110 * (1.0f - xd) + c111 * xd;
        const float c0  = c00 * (1.0f - yd) + c01 * yd;
        const float c1  = c10 * (1.0f - yd) + c11 * yd;
        dens[b] = c0 * (1.0f - zd) + c1 * zd;
        density[((size_t)(b * GG + g)) * PP + p] = dens[b];
    }

    __shared__ float wsum[4][5];
    const int lane = t & 63;
    const int wid  = t >> 6;
    float r0 = dens[0], r1 = dens[1], r2 = dens[2], r3 = dens[3], rd = dist;
#pragma unroll
    for (int off = 32; off > 0; off >>= 1) {
        r0 += __shfl_xor(r0, off);
        r1 += __shfl_xor(r1, off);
        r2 += __shfl_xor(r2, off);
        r3 += __shfl_xor(r3, off);
        rd += __shfl_xor(rd, off);
    }
    if (lane == 0) {
        wsum[wid][0] = r0; wsum[wid][1] = r1; wsum[wid][2] = r2;
        wsum[wid][3] = r3; wsum[wid][4] = rd;
    }
    __syncthreads();
    if (t == 0) {
        float s0 = 0, s1 = 0, s2 = 0, s3 = 0, sd = 0;
#pragma unroll
        for (int w = 0; w < 4; ++w) {
            s0 += wsum[w][0]; s1 += wsum[w][1]; s2 += wsum[w][2];
            s3 += wsum[w][3]; sd += wsum[w][4];
        }
        chunk_sums[((size_t)(0 * GG + g)) * NCHUNK + chunk] = s0;
        chunk_sums[((size_t)(1 * GG + g)) * NCHUNK + chunk] = s1;
        chunk_sums[((size_t)(2 * GG + g)) * NCHUNK + chunk] = s2;
        chunk_sums[((size_t)(3 * GG + g)) * NCHUNK + chunk] = s3;
        dist_part[g * NCHUNK + chunk] = sd;
    }
}

// ---------------------------------------------------------------------------
// Final kernel: per-block exclusive chunk prefix (masked reduction over
// chunk_sums, L2-resident), dist total (wave 0), intra-block scan + scale,
// in place over d_out. Replaces the old scan kernel + memset + atomics.
// grid = (NCHUNK, GG), block = 256. npart = dist partials per g.
// ---------------------------------------------------------------------------
__global__ __launch_bounds__(256) void k_output(
    float* __restrict__ out,
    const float* __restrict__ cs,
    const float* __restrict__ dist_part,
    int npart)
{
    const int chunk = blockIdx.x;
    const int g     = blockIdx.y;
    const int t     = threadIdx.x;
    const int p     = chunk * CHUNK + t;
    const int lane  = t & 63;
    const int wid   = t >> 6;

    __shared__ float exl[4];
    __shared__ float sdist;

    // wave `wid` computes the exclusive prefix for batch b = wid
    {
        const float* row = cs + ((size_t)(wid * GG + g)) * NCHUNK;
        float v = 0.0f;
#pragma unroll
        for (int k = 0; k < 4; ++k) {
            const int idx = lane + 64 * k;
            const float x = row[idx];
            v += (idx < chunk) ? x : 0.0f;
        }
#pragma unroll
        for (int off = 32; off > 0; off >>= 1) v += __shfl_xor(v, off);
        if (lane == 0) exl[wid] = v;
    }
    // wave 0 additionally sums the dist partials for g
    if (wid == 0) {
        float dv = 0.0f;
#pragma unroll
        for (int k = 0; k < 4; ++k) {
            const int idx = lane + 64 * k;
            dv += (idx < npart) ? dist_part[g * npart + idx] : 0.0f;
        }
#pragma unroll
        for (int off = 32; off > 0; off >>= 1) dv += __shfl_xor(dv, off);
        if (lane == 0) sdist = dv;
    }

    float d[BB], v[BB];
#pragma unroll
    for (int b = 0; b < BB; ++b) {
        d[b] = __builtin_nontemporal_load(out + ((size_t)(b * GG + g)) * PP + p);
        v[b] = d[b];
    }

#pragma unroll
    for (int dd = 1; dd < 64; dd <<= 1) {
#pragma unroll
        for (int b = 0; b < BB; ++b) {
            const float n = __shfl_up(v[b], dd);
            if (lane >= dd) v[b] += n;
        }
    }
    __shared__ float ws[4][BB];
    if (lane == 63) {
#pragma unroll
        for (int b = 0; b < BB; ++b) ws[wid][b] = v[b];
    }
    __syncthreads();

    const float step = sdist * (2.0f / (float)(PP - 1));
#pragma unroll
    for (int b = 0; b < BB; ++b) {
        float prefix = 0.0f;
        for (int w = 0; w < wid; ++w) prefix += ws[w][b];
        const float excl = exl[b];
        const float incl = excl + prefix + v[b];
        __builtin_nontemporal_store(step * (incl + 0.5f * d[b]),
            out + ((size_t)(b * GG + g)) * PP + p);
    }
}

// ---------------------------------------------------------------------------
extern "C" void kernel_launch(void* const* d_in, const int* in_sizes, int n_in,
                              void* d_out, int out_size, void* d_ws, size_t ws_size,
                              hipStream_t stream)
{
    const float* ct     = (const float*)d_in[0];
    const float* coords = (const float*)d_in[1];
    float* out = (float*)d_out;

    const size_t volBytes = (size_t)HDW * BB * sizeof(_Float16);        // 256 MiB
    const size_t csCount  = (size_t)BB * GG * NCHUNK;
    const size_t dpCount  = (size_t)GG * NCHUNK;    // max of both paths
    const size_t needed   = volBytes + (csCount + dpCount) * sizeof(float);

    if (ws_size >= needed) {
        _Float16* tv       = (_Float16*)d_ws;
        float* chunk_sums  = (float*)((char*)d_ws + volBytes);
        float* dist_part   = chunk_sums + csCount;

        k_transpose<<<NBRICK / 2 / 256, 256, 0, stream>>>(ct, tv);
        k_density_h<<<dim3(NCHUNK / CPB, GG), 256, 0, stream>>>(tv, coords, out, chunk_sums, dist_part);
        k_output<<<dim3(NCHUNK, GG), 256, 0, stream>>>(out, chunk_sums, dist_part, NPART);
    } else {
        float* chunk_sums  = (float*)d_ws;
        float* dist_part   = chunk_sums + csCount;

        k_density<<<dim3(NCHUNK, GG), 256, 0, stream>>>(ct, coords, out, chunk_sums, dist_part);
        k_output<<<dim3(NCHUNK, GG), 256, 0, stream>>>(out, chunk_sums, dist_part, NCHUNK);
    }
}

// Round 6
// 1008.391 us; speedup vs baseline: 1.0349x; 1.0349x over previous
//
#include <hip/hip_runtime.h>
#include <math.h>

// Problem constants (fixed by setup_inputs)
#define BB 4
#define HH 128
#define DD 512
#define WW 512
#define GG 72
#define PP 65536
#define CHUNK 256
#define NCHUNK (PP / CHUNK)          // 256
#define HDW (HH * DD * WW)           // 33,554,432
#define NBRICK (HDW / 8)             // 4,194,304 bricks of 2x2x2 voxels
#define CPB 2                        // chunks per density block (2 = measured optimum; 4 regressed: VGPR/occupancy)
#define NPART (NCHUNK / CPB)         // 128 dist partials per g (fast path)

typedef _Float16 half4 __attribute__((ext_vector_type(4)));
typedef _Float16 half8 __attribute__((ext_vector_type(8)));
typedef float f4 __attribute__((ext_vector_type(4)));   // NT-load-compatible

// ---------------------------------------------------------------------------
// Transpose + quantize into 64B bricks:
//   ct [B,H,D,W] fp32  ->  tv bricks: brick(bz,by,bx) holds 2x2x2 voxels x 4
//   batches fp16, inner layout [oz][oy][ox][b] -> 32 halves = 64 B = 1 line.
// One thread per brick-PAIR (adjacent in x): f4 NT reads, 128 B write.
// NT on ct reads so the 512 MiB stream doesn't evict the tv writes from L3 —
// the density pass depends on tv being L3-resident.
// ---------------------------------------------------------------------------
__global__ __launch_bounds__(256) void k_transpose(
    const float* __restrict__ ct, _Float16* __restrict__ tv)
{
    const int n2  = blockIdx.x * 256 + threadIdx.x;  // brick-pair index
    const int bxp = n2 & 127;                        // 128 pairs per x-row
    const int by  = (n2 >> 7) & 255;                 // DD/2
    const int bz  = n2 >> 15;                        // HH/2
    const size_t base = ((size_t)(2 * bz) * DD + 2 * by) * WW + 4 * bxp;

    half8 o00, o01, o02, o03;   // brick 0: inner pairs (oz,oy) = 00,01,10,11
    half8 o10, o11, o12, o13;   // brick 1
#pragma unroll
    for (int b = 0; b < BB; ++b) {
        const float* v = ct + (size_t)b * HDW + base;
        const f4 f00 = __builtin_nontemporal_load((const f4*)(v));
        const f4 f01 = __builtin_nontemporal_load((const f4*)(v + WW));
        const f4 f10 = __builtin_nontemporal_load((const f4*)(v + (size_t)DD * WW));
        const f4 f11 = __builtin_nontemporal_load((const f4*)(v + (size_t)DD * WW + WW));
        o00[b] = (_Float16)f00[0]; o00[4 + b] = (_Float16)f00[1];
        o01[b] = (_Float16)f01[0]; o01[4 + b] = (_Float16)f01[1];
        o02[b] = (_Float16)f10[0]; o02[4 + b] = (_Float16)f10[1];
        o03[b] = (_Float16)f11[0]; o03[4 + b] = (_Float16)f11[1];
        o10[b] = (_Float16)f00[2]; o10[4 + b] = (_Float16)f00[3];
        o11[b] = (_Float16)f01[2]; o11[4 + b] = (_Float16)f01[3];
        o12[b] = (_Float16)f10[2]; o12[4 + b] = (_Float16)f10[3];
        o13[b] = (_Float16)f11[2]; o13[4 + b] = (_Float16)f11[3];
    }
    _Float16* dst = tv + (size_t)n2 * 64;   // two consecutive 64 B bricks
    *(half8*)(dst)      = o00;
    *(half8*)(dst + 8)  = o01;
    *(half8*)(dst + 16) = o02;
    *(half8*)(dst + 24) = o03;
    *(half8*)(dst + 32) = o10;
    *(half8*)(dst + 40) = o11;
    *(half8*)(dst + 48) = o12;
    *(half8*)(dst + 56) = o13;
}

// half-element offset of corner voxel (zc,yc,xc) in the brick volume
__device__ __forceinline__ int brick_off(int zc, int yc, int xc)
{
    const int brick = ((zc >> 1) << 16) | ((yc >> 1) << 8) | (xc >> 1);
    const int inner = ((zc & 1) << 2) | ((yc & 1) << 1) | (xc & 1);
    return (brick << 5) | (inner << 2);
}

struct PS {
    int i[8];
    float xd, yd, zd;
};

__device__ __forceinline__ PS setup_brick(float cx, float cy, float cz)
{
    const float x = fminf(fmaxf(cx, 0.0f), (float)(WW - 1));
    const float y = fminf(fmaxf(cy, 0.0f), (float)(DD - 1));
    const float z = fminf(fmaxf(cz, 0.0f), (float)(HH - 1));
    const int x0 = (int)floorf(x);
    const int y0 = (int)floorf(y);
    const int z0 = (int)floorf(z);
    const int x1 = min(x0 + 1, WW - 1);
    const int y1 = min(y0 + 1, DD - 1);
    const int z1 = min(z0 + 1, HH - 1);
    PS s;
    s.xd = x - (float)x0;
    s.yd = y - (float)y0;
    s.zd = z - (float)z0;
    s.i[0] = brick_off(z0, y0, x0); s.i[1] = brick_off(z0, y0, x1);
    s.i[2] = brick_off(z0, y1, x0); s.i[3] = brick_off(z0, y1, x1);
    s.i[4] = brick_off(z1, y0, x0); s.i[5] = brick_off(z1, y0, x1);
    s.i[6] = brick_off(z1, y1, x0); s.i[7] = brick_off(z1, y1, x1);
    return s;
}

__device__ __forceinline__ void gather8(
    const _Float16* __restrict__ tv, const PS& s, half4 A[8])
{
#pragma unroll
    for (int k = 0; k < 8; ++k) A[k] = *(const half4*)(tv + (size_t)s.i[k]);
}

__device__ __forceinline__ void lerp_store(
    const half4 A[8], const PS& s, float dens[BB],
    float* __restrict__ density, int g, int p)
{
#pragma unroll
    for (int b = 0; b < BB; ++b) {
        const float c000 = (float)A[0][b], c001 = (float)A[1][b];
        const float c010 = (float)A[2][b], c011 = (float)A[3][b];
        const float c100 = (float)A[4][b], c101 = (float)A[5][b];
        const float c110 = (float)A[6][b], c111 = (float)A[7][b];
        const float c00 = c000 * (1.0f - s.xd) + c001 * s.xd;
        const float c01 = c010 * (1.0f - s.xd) + c011 * s.xd;
        const float c10 = c100 * (1.0f - s.xd) + c101 * s.xd;
        const float c11 = c110 * (1.0f - s.xd) + c111 * s.xd;
        const float c0  = c00 * (1.0f - s.yd) + c01 * s.yd;
        const float c1  = c10 * (1.0f - s.yd) + c11 * s.yd;
        dens[b] = c0 * (1.0f - s.zd) + c1 * s.zd;
        __builtin_nontemporal_store(dens[b],
            density + ((size_t)(b * GG + g)) * PP + p);
    }
}

// ---------------------------------------------------------------------------
// Density kernel, single pass, 2 chunks per block (2 points per thread):
// 16 unmasked outstanding gather loads per thread — the measured MLP/TLP
// optimum (4 pts/thread regressed: VGPR pressure halved occupancy).
// tv is L3-resident after the transpose; all streaming traffic (coords,
// density out) is non-temporal so it stays resident. Each block owns chunks
// c0,c0+1 exclusively -> chunk_sums and dist_part plain stores (no atomics).
// grid = (NCHUNK/2, GG), block = 256.
// ---------------------------------------------------------------------------
__global__ __launch_bounds__(256) void k_density_h(
    const _Float16* __restrict__ tv,    // brick volume fp16
    const float* __restrict__ coords,   // [G, P, 3]
    float* __restrict__ density,        // [B*G, P]  (aliases d_out)
    float* __restrict__ chunk_sums,     // [B*G, NCHUNK]
    float* __restrict__ dist_part)      // [G, NPART]
{
    const int cpair = blockIdx.x;            // handles chunks c0, c0+1
    const int g     = blockIdx.y;
    const int t     = threadIdx.x;
    const int c0    = cpair * CPB;
    const int p0    = c0 * CHUNK + t;        // p1 = p0 + 256

    __shared__ float cbuf[(CPB * CHUNK + 1) * 3];
    const bool last  = (cpair == NPART - 1);
    const int  nload = last ? CPB * CHUNK * 3 : (CPB * CHUNK + 1) * 3;
    const float* src = coords + ((size_t)g * PP + (size_t)c0 * CHUNK) * 3;
    for (int i = t; i < nload; i += 256)
        cbuf[i] = __builtin_nontemporal_load(src + i);
    __syncthreads();

    const float ax = cbuf[3 * t + 0], ay = cbuf[3 * t + 1], az = cbuf[3 * t + 2];
    const int   u  = t + 256;
    const float bx = cbuf[3 * u + 0], by = cbuf[3 * u + 1], bz = cbuf[3 * u + 2];

    float dist_tot;
    {
        const float dx = cbuf[3 * (t + 1) + 0] - ax;
        const float dy = cbuf[3 * (t + 1) + 1] - ay;
        const float dz = cbuf[3 * (t + 1) + 2] - az;
        dist_tot = sqrtf(dx * dx + dy * dy + dz * dz);   // p0 <= 65279 always
    }
    if (!(last && t == CHUNK - 1)) {
        const float dx = cbuf[3 * (u + 1) + 0] - bx;
        const float dy = cbuf[3 * (u + 1) + 1] - by;
        const float dz = cbuf[3 * (u + 1) + 2] - bz;
        dist_tot += sqrtf(dx * dx + dy * dy + dz * dz);
    }

    const PS s0 = setup_brick(ax, ay, az);
    const PS s1 = setup_brick(bx, by, bz);

    // Issue both gather batches before any lerp so 16 loads overlap.
    half4 A0[8], A1[8];
    gather8(tv, s0, A0);
    gather8(tv, s1, A1);

    float dens0[BB], dens1[BB];
    lerp_store(A0, s0, dens0, density, g, p0);
    lerp_store(A1, s1, dens1, density, g, p0 + 256);

    // Fused block reduction: 8 chunk sums + 1 dist total.
    __shared__ float wsum[4][9];
    const int lane = t & 63;
    const int wid  = t >> 6;
    float r[9] = {dens0[0], dens0[1], dens0[2], dens0[3],
                  dens1[0], dens1[1], dens1[2], dens1[3], dist_tot};
#pragma unroll
    for (int off = 32; off > 0; off >>= 1) {
#pragma unroll
        for (int k = 0; k < 9; ++k) r[k] += __shfl_xor(r[k], off);
    }
    if (lane == 0) {
#pragma unroll
        for (int k = 0; k < 9; ++k) wsum[wid][k] = r[k];
    }
    __syncthreads();
    if (t == 0) {
        float sarr[9];
#pragma unroll
        for (int k = 0; k < 9; ++k)
            sarr[k] = wsum[0][k] + wsum[1][k] + wsum[2][k] + wsum[3][k];
#pragma unroll
        for (int b = 0; b < BB; ++b) {
            chunk_sums[((size_t)(b * GG + g)) * NCHUNK + c0]     = sarr[b];
            chunk_sums[((size_t)(b * GG + g)) * NCHUNK + c0 + 1] = sarr[4 + b];
        }
        dist_part[g * NPART + cpair] = sarr[8];
    }
}

// ---------------------------------------------------------------------------
// Fallback density kernel (fp32 direct gather) — used if ws too small.
// Writes dist_part with NCHUNK partials per g.
// ---------------------------------------------------------------------------
__global__ __launch_bounds__(256) void k_density(
    const float* __restrict__ ct,
    const float* __restrict__ coords,
    float* __restrict__ density,
    float* __restrict__ chunk_sums,
    float* __restrict__ dist_part)      // [G, NCHUNK]
{
    const int chunk = blockIdx.x;
    const int g     = blockIdx.y;
    const int t     = threadIdx.x;
    const int p     = chunk * CHUNK + t;

    __shared__ float cbuf[(CHUNK + 1) * 3];
    const int nload = (chunk == NCHUNK - 1) ? CHUNK * 3 : (CHUNK + 1) * 3;
    const float* src = coords + ((size_t)g * PP + (size_t)chunk * CHUNK) * 3;
    for (int i = t; i < nload; i += CHUNK) cbuf[i] = src[i];
    __syncthreads();

    const float cx = cbuf[3 * t + 0];
    const float cy = cbuf[3 * t + 1];
    const float cz = cbuf[3 * t + 2];

    float dist = 0.0f;
    if (p < PP - 1) {
        const int nt = 3 * (t + 1);
        const float dx = cbuf[nt + 0] - cx;
        const float dy = cbuf[nt + 1] - cy;
        const float dz = cbuf[nt + 2] - cz;
        dist = sqrtf(dx * dx + dy * dy + dz * dz);
    }

    const float x = fminf(fmaxf(cx, 0.0f), (float)(WW - 1));
    const float y = fminf(fmaxf(cy, 0.0f), (float)(DD - 1));
    const float z = fminf(fmaxf(cz, 0.0f), (float)(HH - 1));
    const int x0 = (int)floorf(x);
    const int y0 = (int)floorf(y);
    const int z0 = (int)floorf(z);
    const int x1 = min(x0 + 1, WW - 1);
    const int y1 = min(y0 + 1, DD - 1);
    const int z1 = min(z0 + 1, HH - 1);
    const float xd = x - (float)x0, yd = y - (float)y0, zd = z - (float)z0;

    const int b00 = (z0 * DD + y0) * WW;
    const int b01 = (z0 * DD + y1) * WW;
    const int b10 = (z1 * DD + y0) * WW;
    const int b11 = (z1 * DD + y1) * WW;

    float dens[BB];
#pragma unroll
    for (int b = 0; b < BB; ++b) {
        const float* v = ct + (size_t)b * HDW;
        const float c000 = v[b00 + x0], c001 = v[b00 + x1];
        const float c010 = v[b01 + x0], c011 = v[b01 + x1];
        const float c100 = v[b10 + x0], c101 = v[b10 + x1];
        const float c110 = v[b11 + x0], c111 = v[b11 + x1];
        const float c00 = c000 * (1.0f - xd) + c001 * xd;
        const float c01 = c010 * (1.0f - xd) + c011 * xd;
        const float c10 = c100 * (1.0f - xd) + c101 * xd;
        const float c11 = c110 * (1.0f - xd) + c111 * xd;
        const float c0  = c00 * (1.0f - yd) + c01 * yd;
        const float c1  = c10 * (1.0f - yd) + c11 * yd;
        dens[b] = c0 * (1.0f - zd) + c1 * zd;
        density[((size_t)(b * GG + g)) * PP + p] = dens[b];
    }

    __shared__ float wsum[4][5];
    const int lane = t & 63;
    const int wid  = t >> 6;
    float r0 = dens[0], r1 = dens[1], r2 = dens[2], r3 = dens[3], rd = dist;
#pragma unroll
    for (int off = 32; off > 0; off >>= 1) {
        r0 += __shfl_xor(r0, off);
        r1 += __shfl_xor(r1, off);
        r2 += __shfl_xor(r2, off);
        r3 += __shfl_xor(r3, off);
        rd += __shfl_xor(rd, off);
    }
    if (lane == 0) {
        wsum[wid][0] = r0; wsum[wid][1] = r1; wsum[wid][2] = r2;
        wsum[wid][3] = r3; wsum[wid][4] = rd;
    }
    __syncthreads();
    if (t == 0) {
        float s0 = 0, s1 = 0, s2 = 0, s3 = 0, sd = 0;
#pragma unroll
        for (int w = 0; w < 4; ++w) {
            s0 += wsum[w][0]; s1 += wsum[w][1]; s2 += wsum[w][2];
            s3 += wsum[w][3]; sd += wsum[w][4];
        }
        chunk_sums[((size_t)(0 * GG + g)) * NCHUNK + chunk] = s0;
        chunk_sums[((size_t)(1 * GG + g)) * NCHUNK + chunk] = s1;
        chunk_sums[((size_t)(2 * GG + g)) * NCHUNK + chunk] = s2;
        chunk_sums[((size_t)(3 * GG + g)) * NCHUNK + chunk] = s3;
        dist_part[g * NCHUNK + chunk] = sd;
    }
}

// ---------------------------------------------------------------------------
// Final kernel: per-block exclusive chunk prefix (masked reduction over
// chunk_sums, L2-resident), dist total (wave 0), intra-block scan + scale,
// in place over d_out. Replaces the old scan kernel + memset + atomics.
// grid = (NCHUNK, GG), block = 256. npart = dist partials per g.
// ---------------------------------------------------------------------------
__global__ __launch_bounds__(256) void k_output(
    float* __restrict__ out,
    const float* __restrict__ cs,
    const float* __restrict__ dist_part,
    int npart)
{
    const int chunk = blockIdx.x;
    const int g     = blockIdx.y;
    const int t     = threadIdx.x;
    const int p     = chunk * CHUNK + t;
    const int lane  = t & 63;
    const int wid   = t >> 6;

    // issue the density loads first so they overlap the prefix reductions
    float d[BB], v[BB];
#pragma unroll
    for (int b = 0; b < BB; ++b)
        d[b] = __builtin_nontemporal_load(out + ((size_t)(b * GG + g)) * PP + p);

    __shared__ float exl[4];
    __shared__ float sdist;

    // wave `wid` computes the exclusive prefix for batch b = wid
    {
        const float* row = cs + ((size_t)(wid * GG + g)) * NCHUNK;
        float pv = 0.0f;
#pragma unroll
        for (int k = 0; k < 4; ++k) {
            const int idx = lane + 64 * k;
            const float x = row[idx];
            pv += (idx < chunk) ? x : 0.0f;
        }
#pragma unroll
        for (int off = 32; off > 0; off >>= 1) pv += __shfl_xor(pv, off);
        if (lane == 0) exl[wid] = pv;
    }
    // wave 0 additionally sums the dist partials for g
    if (wid == 0) {
        float dv = 0.0f;
#pragma unroll
        for (int k = 0; k < 4; ++k) {
            const int idx = lane + 64 * k;
            dv += (idx < npart) ? dist_part[g * npart + idx] : 0.0f;
        }
#pragma unroll
        for (int off = 32; off > 0; off >>= 1) dv += __shfl_xor(dv, off);
        if (lane == 0) sdist = dv;
    }

#pragma unroll
    for (int b = 0; b < BB; ++b) v[b] = d[b];

#pragma unroll
    for (int dd = 1; dd < 64; dd <<= 1) {
#pragma unroll
        for (int b = 0; b < BB; ++b) {
            const float n = __shfl_up(v[b], dd);
            if (lane >= dd) v[b] += n;
        }
    }
    __shared__ float ws[4][BB];
    if (lane == 63) {
#pragma unroll
        for (int b = 0; b < BB; ++b) ws[wid][b] = v[b];
    }
    __syncthreads();

    const float step = sdist * (2.0f / (float)(PP - 1));
#pragma unroll
    for (int b = 0; b < BB; ++b) {
        float prefix = 0.0f;
        for (int w = 0; w < wid; ++w) prefix += ws[w][b];
        const float excl = exl[b];
        const float incl = excl + prefix + v[b];
        __builtin_nontemporal_store(step * (incl + 0.5f * d[b]),
            out + ((size_t)(b * GG + g)) * PP + p);
    }
}

// ---------------------------------------------------------------------------
extern "C" void kernel_launch(void* const* d_in, const int* in_sizes, int n_in,
                              void* d_out, int out_size, void* d_ws, size_t ws_size,
                              hipStream_t stream)
{
    const float* ct     = (const float*)d_in[0];
    const float* coords = (const float*)d_in[1];
    float* out = (float*)d_out;

    const size_t volBytes = (size_t)HDW * BB * sizeof(_Float16);        // 256 MiB
    const size_t csCount  = (size_t)BB * GG * NCHUNK;
    const size_t dpCount  = (size_t)GG * NCHUNK;    // max of both paths
    const size_t needed   = volBytes + (csCount + dpCount) * sizeof(float);

    if (ws_size >= needed) {
        _Float16* tv       = (_Float16*)d_ws;
        float* chunk_sums  = (float*)((char*)d_ws + volBytes);
        float* dist_part   = chunk_sums + csCount;

        k_transpose<<<NBRICK / 2 / 256, 256, 0, stream>>>(ct, tv);
        k_density_h<<<dim3(NCHUNK / CPB, GG), 256, 0, stream>>>(tv, coords, out, chunk_sums, dist_part);
        k_output<<<dim3(NCHUNK, GG), 256, 0, stream>>>(out, chunk_sums, dist_part, NPART);
    } else {
        float* chunk_sums  = (float*)d_ws;
        float* dist_part   = chunk_sums + csCount;

        k_density<<<dim3(NCHUNK, GG), 256, 0, stream>>>(ct, coords, out, chunk_sums, dist_part);
        k_output<<<dim3(NCHUNK, GG), 256, 0, stream>>>(out, chunk_sums, dist_part, NCHUNK);
    }
}